// Round 1
// baseline (568.926 us; speedup 1.0000x reference)
//
#include <hip/hip_runtime.h>
#include <math.h>

// Problem constants (from reference): B=4, S=4096, H=32, D=64, STEP=32, N_STEPS=128
#define BB 4
#define SS 4096
#define HH 32
#define DD 64
#define STEPF 32.0f
#define NSTEPS 128

#define SUBC 64          // positions per sub-chunk (one wave each)
#define SC_PER_BH (SS / SUBC)   // 64 sub-chunks per (b,h)
#define WAVES 4          // waves per block (256 threads)

__device__ __forceinline__ float wave_sum64(float v) {
    v += __shfl_xor(v, 1);
    v += __shfl_xor(v, 2);
    v += __shfl_xor(v, 4);
    v += __shfl_xor(v, 8);
    v += __shfl_xor(v, 16);
    v += __shfl_xor(v, 32);
    return v;
}

// Kernel A: per-sub-chunk sums of kn = relu(k)/(||relu(k)||+1e-6) over 64 positions.
// Grid: (SC_PER_BH/WAVES, H, B), block 256. lane = dim d, one wave per sub-chunk.
__global__ __launch_bounds__(256) void knorm_subchunk_sums(
    const float* __restrict__ k, float* __restrict__ sums) {
    const int lane = threadIdx.x & 63;
    const int wave = threadIdx.x >> 6;
    const int sc = blockIdx.x * WAVES + wave;
    const int h = blockIdx.y;
    const int b = blockIdx.z;
    const int p0 = sc * SUBC;
    size_t base = ((size_t)b * SS + p0) * (HH * DD) + (size_t)h * DD + lane;
    float acc = 0.f;
#pragma unroll 4
    for (int i = 0; i < SUBC; ++i) {
        float kv = k[base + (size_t)i * (HH * DD)];
        float kr = fmaxf(kv, 0.f);
        float ss = wave_sum64(kr * kr);
        float kn = kr / (sqrtf(ss) + 1e-6f);
        acc += kn;
    }
    sums[(((size_t)b * HH + h) * SC_PER_BH + sc) * DD + lane] = acc;
}

// Kernel B: exclusive-offset from sub-chunk sums, then sequential 64-position pass:
// cumk update, pos = qn . cumk, scalar cos/sin interp, rotate-half RoPE, write q_out/k_out.
__global__ __launch_bounds__(256) void rope_apply(
    const float* __restrict__ q, const float* __restrict__ k,
    const float* __restrict__ cosst, const float* __restrict__ sinst,
    const float* __restrict__ sums,
    float* __restrict__ outq, float* __restrict__ outk) {
    const int lane = threadIdx.x & 63;
    const int wave = threadIdx.x >> 6;
    const int sc = blockIdx.x * WAVES + wave;
    const int h = blockIdx.y;
    const int b = blockIdx.z;

    // exclusive prefix over earlier sub-chunks (coalesced 256B rows; array is 2 MiB -> L2/L3)
    const float* srow = sums + (((size_t)b * HH + h) * SC_PER_BH) * DD + lane;
    float off = 0.f;
    for (int cc = 0; cc < sc; ++cc) off += srow[(size_t)cc * DD];

    const int p0 = sc * SUBC;
    size_t base = ((size_t)b * SS + p0) * (HH * DD) + (size_t)h * DD + lane;
    float cumk = off;
#pragma unroll 4
    for (int i = 0; i < SUBC; ++i) {
        size_t idx = base + (size_t)i * (HH * DD);
        float kv = k[idx];
        float qv = q[idx];

        float kr = fmaxf(kv, 0.f);
        float kss = wave_sum64(kr * kr);
        float kn = kr / (sqrtf(kss) + 1e-6f);
        cumk += kn;

        float qr = fmaxf(qv, 0.f);
        float qss = wave_sum64(qr * qr);
        float qn = qr / (sqrtf(qss) + 1e-6f);

        float dot = wave_sum64(qn * cumk);
        float pos = dot * (1.0f / STEPF);
        pos = fminf(fmaxf(pos, 0.f), (float)(NSTEPS - 1));
        float pf = floorf(pos);
        int pfi = (int)pf;
        float frac = pos - pf;
        int pci = min(pfi + 1, NSTEPS - 1);

        // tables are (NSTEPS, DD); reference uses column 0 only
        float c0 = cosst[(size_t)pfi * DD];
        float c1 = cosst[(size_t)pci * DD];
        float s0 = sinst[(size_t)pfi * DD];
        float s1 = sinst[(size_t)pci * DD];
        float cosp = c0 + frac * (c1 - c0);
        float sinp = s0 + frac * (s1 - s0);

        // rotate_half: rot(x)[d] = d<32 ? -x[d+32] : x[d-32]
        float qo = __shfl_xor(qv, 32);
        float rq = (lane < 32) ? -qo : qo;
        float ko = __shfl_xor(kv, 32);
        float rk = (lane < 32) ? -ko : ko;

        outq[idx] = qv * cosp + rq * sinp;
        outk[idx] = kv * cosp + rk * sinp;
    }
}

extern "C" void kernel_launch(void* const* d_in, const int* in_sizes, int n_in,
                              void* d_out, int out_size, void* d_ws, size_t ws_size,
                              hipStream_t stream) {
    const float* q = (const float*)d_in[0];
    const float* k = (const float*)d_in[1];
    // d_in[2] = v, unused by reference outputs
    const float* cosst = (const float*)d_in[3];
    const float* sinst = (const float*)d_in[4];
    // d_in[5] = offset, unused by reference

    float* outq = (float*)d_out;
    float* outk = outq + (size_t)BB * SS * HH * DD;
    float* sums = (float*)d_ws;  // B*H*SC_PER_BH*D floats = 2 MiB

    dim3 grid(SC_PER_BH / WAVES, HH, BB);  // (16, 32, 4) = 2048 blocks
    knorm_subchunk_sums<<<grid, 256, 0, stream>>>(k, sums);
    rope_apply<<<grid, 256, 0, stream>>>(q, k, cosst, sinst, sums, outq, outk);
}